// Round 7
// baseline (902.400 us; speedup 1.0000x reference)
//
#include <hip/hip_runtime.h>
#include <stdint.h>

using f32x4  = __attribute__((ext_vector_type(4))) float;
using f32x16 = __attribute__((ext_vector_type(16))) float;
using bf16x8 = __attribute__((ext_vector_type(8))) __bf16;

#define GLOAD_LDS16(src, dst) __builtin_amdgcn_global_load_lds(                 \
    (const __attribute__((address_space(1))) void*)(src),                      \
    (__attribute__((address_space(3))) void*)(dst), 16, 0, 0)

// ===========================================================================
// Fragment-major layout for mfma_f32_32x32x16_bf16:
//   A/B operand: row|col = lane&31, k = (lane>>5)*8 + e  (8 bf16 = 4 VGPR).
//   128x128 tile = 32 frags, f = mt*8 + ks16 (mt = row/32, ks16 = k/16).
//   Unit u = f*64 + lane; lane's frag = contiguous 16B at u*16.
//   B tiles half-contiguous for the ring: unit w = h*1024 + g*64 + lane,
//   g = nt*4 + (ks16&3), half h = ks16>>2 (K=64 per half).
//   C/D: col = lane&31, row = (reg&3) + 8*(reg>>2) + 4*(lane>>5)  [m74/m101].
// ===========================================================================

// x (fp32, row-major N x 256) -> actA frag-major bf16 (I=256, NCH=2)
__global__ void cvt_x_kernel(const float* __restrict__ x, __bf16* __restrict__ out) {
    const int u    = blockIdx.x * 256 + threadIdx.x;
    const int lane = u & 63;
    const int f    = (u >> 6) & 31;      // mt*8 + ks16
    const int c    = (u >> 11) & 1;
    const int rb   = u >> 12;
    const int row  = rb * 128 + ((f >> 3) << 5) + (lane & 31);
    const int i    = c * 128 + ((f & 7) << 4) + ((lane >> 5) << 3);
    const float4 a = *(const float4*)(x + (size_t)row * 256 + i);
    const float4 b = *(const float4*)(x + (size_t)row * 256 + i + 4);
    bf16x8 pv;
    pv[0] = (__bf16)a.x; pv[1] = (__bf16)a.y; pv[2] = (__bf16)a.z; pv[3] = (__bf16)a.w;
    pv[4] = (__bf16)b.x; pv[5] = (__bf16)b.y; pv[6] = (__bf16)b.z; pv[7] = (__bf16)b.w;
    *(bf16x8*)(out + (size_t)u * 8) = pv;
}

// W (R x O x I fp32) -> Bt frag-major bf16, half-contiguous unit order.
template<int I, int O>
__global__ void prep_w_kernel(const float* __restrict__ W, __bf16* __restrict__ Bt) {
    constexpr int NCH = I >> 7;
    const int u    = blockIdx.x * 256 + threadIdx.x;     // < NCH*2048
    const int r    = blockIdx.y;
    const int nb   = blockIdx.z;
    const int lane = u & 63;
    const int g    = (u >> 6) & 15;      // nt*4 + (ks16&3)
    const int h    = (u >> 10) & 1;
    const int c    = u >> 11;
    const int nt   = g >> 2;
    const int ks16 = (h << 2) + (g & 3);
    const int o    = nb * 128 + nt * 32 + (lane & 31);   // output col (B^T row)
    const int i    = c * 128 + ks16 * 16 + ((lane >> 5) << 3);
    const float* src = W + ((size_t)r * O + o) * I + i;
    const float4 a = *(const float4*)src;
    const float4 b = *(const float4*)(src + 4);
    bf16x8 pv;
    pv[0] = (__bf16)a.x; pv[1] = (__bf16)a.y; pv[2] = (__bf16)a.z; pv[3] = (__bf16)a.w;
    pv[4] = (__bf16)b.x; pv[5] = (__bf16)b.y; pv[6] = (__bf16)b.z; pv[7] = (__bf16)b.w;
    *(bf16x8*)(Bt + ((((size_t)nb * 9 + r) * NCH + c) * 2048 + (u & 2047)) * 8) = pv;
}

// bias tiles: per nb one 128x64(K) tile, 16 frags f = mt*4 + ks16
template<int O>
__global__ void prep_bias_kernel(const float* __restrict__ b, __bf16* __restrict__ BtB) {
    const int u    = blockIdx.x * 256 + threadIdx.x;     // < (O/128)*1024
    const int nb   = u >> 10;
    const int q    = u & 1023;
    const int lane = q & 63;
    const int f    = q >> 6;
    const int o    = nb * 128 + ((f >> 2) << 5) + (lane & 31);
    const int kb   = ((f & 3) << 4) + ((lane >> 5) << 3);
    bf16x8 pv;
#pragma unroll
    for (int e = 0; e < 8; ++e) {
        const int k = kb + e;
        pv[e] = (k < 9) ? (__bf16)b[(size_t)k * O + o] : (__bf16)0.f;
    }
    *(bf16x8*)(BtB + (size_t)u * 8) = pv;
}

// ---------------------------------------------------------------------------
// Relation-mixed GEMM, 32x32x16 MFMA, A-in-registers + B ring-4 pipeline:
//   y[n,o] = sum_r e[n,r]*(sum_i x[n,i] W[r,o,i]) + sum_r e[n,r] b[r,o]
// Per 128-col i-chunk: af[2][8] global->VGPR once (reused 9 r's); B halves
// stream through 4 LDS buffers, counted vmcnt(12) steady state. Sub-phase
// s=2r+h: wait -> barrier -> read bv -> lgkm0 -> barrier -> refill -> 16 MFMA.
// Fold acc += e_r * acc2 per r. Bias = one extra K=64 step.
// ---------------------------------------------------------------------------
template<int I, int O, bool RELU, bool OUTF32>
__global__ __launch_bounds__(256, 2)
void kg_gemm(const __bf16* __restrict__ A, const float* __restrict__ E,
             const __bf16* __restrict__ Bt, const __bf16* __restrict__ BtB,
             void* __restrict__ Outv) {
    constexpr int NCH = I >> 7;
    constexpr int NBN = O >> 7;
    static_assert((I & 127) == 0 && (O & 127) == 0, "tile divisibility");

    __shared__ __align__(16) char lds[4 * 16384 + 4608];
    float* const ldsE = (float*)(lds + 65536);   // Et[r][row]

    const int tid  = threadIdx.x;
    const int nwg  = gridDim.x;
    const int braw = blockIdx.x;
    const int bid  = (braw & 7) * (nwg >> 3) + (braw >> 3);   // XCD swizzle (nwg%8==0)
    const int rb   = bid / NBN;
    const int nb   = bid % NBN;
    const int bm0  = rb << 7;
    const int bn0  = nb << 7;
    const int lane = tid & 63;
    const int wid  = tid >> 6;
    const int mtb  = (wid >> 1) << 1;   // wave tile-row base (0 or 2)
    const int ntb  = (wid & 1) << 1;    // wave tile-col base (0 or 2)
    const int wr64 = mtb << 5;
    const int l31  = lane & 31;
    const int lhi  = lane >> 5;

    if (tid < 128) {
        const float* e = E + (size_t)(bm0 + tid) * 9;
#pragma unroll
        for (int q = 0; q < 9; ++q) ldsE[q * 128 + tid] = e[q];
    }

    f32x16 zero16;
#pragma unroll
    for (int j = 0; j < 16; ++j) zero16[j] = 0.f;
    f32x16 acc[2][2];
#pragma unroll
    for (int mt = 0; mt < 2; ++mt)
#pragma unroll
        for (int nt = 0; nt < 2; ++nt) acc[mt][nt] = zero16;

    const size_t Abase = (size_t)rb * NCH * 2048;       // units
    const size_t Bbase = (size_t)nb * 9 * NCH * 2048;   // units

    // stage sub-phase s (r=s>>1, h=s&1) into buf[s&3]
    auto stageS = [&](int s, int c) {
        const __bf16* src = Bt + (Bbase + ((size_t)(s >> 1) * NCH + c) * 2048
                                  + (size_t)((s & 1) << 10)) * 8;
        char* dst = lds + ((s & 3) << 14);
#pragma unroll
        for (int it = 0; it < 4; ++it) {
            const int q = it * 256 + tid;
            GLOAD_LDS16(src + (size_t)q * 8, dst + q * 16);
        }
    };

#pragma unroll 1
    for (int c = 0; c < NCH; ++c) {
        asm volatile("s_waitcnt lgkmcnt(0)" ::: "memory");
        __builtin_amdgcn_s_barrier();
        __builtin_amdgcn_sched_barrier(0);
        // A fragments: global -> VGPR, once per chunk (before B stages so the
        // s=0 vmcnt(12) also covers them)
        bf16x8 af[2][8];
        {
            const __bf16* Ab = A + (Abase + (size_t)c * 2048) * 8;
#pragma unroll
            for (int mt = 0; mt < 2; ++mt)
#pragma unroll
                for (int ks = 0; ks < 8; ++ks)
                    af[mt][ks] = *(const bf16x8*)(Ab + ((size_t)((((mtb + mt) << 3) + ks) << 6) + lane) * 8);
        }
        stageS(0, c); stageS(1, c); stageS(2, c); stageS(3, c);
#pragma unroll 1
        for (int r = 0; r < 9; ++r) {
            f32x16 acc2[2][2];
#pragma unroll
            for (int h = 0; h < 2; ++h) {
                const int s = 2 * r + h;
                if (h == 0) {
                    if (r < 8) asm volatile("s_waitcnt vmcnt(12)" ::: "memory");
                    else       asm volatile("s_waitcnt vmcnt(4)"  ::: "memory");
                } else {
                    if (r < 7)       asm volatile("s_waitcnt vmcnt(12)" ::: "memory");
                    else if (r == 7) asm volatile("s_waitcnt vmcnt(8)"  ::: "memory");
                    else             asm volatile("s_waitcnt vmcnt(0)"  ::: "memory");
                }
                __builtin_amdgcn_s_barrier();
                __builtin_amdgcn_sched_barrier(0);
                const char* bp = lds + ((s & 3) << 14);
                bf16x8 bv[2][4];
#pragma unroll
                for (int nt = 0; nt < 2; ++nt)
#pragma unroll
                    for (int km = 0; km < 4; ++km)
                        bv[nt][km] = *(const bf16x8*)(bp + (((((ntb + nt) << 2) + km) << 6) + lane) * 16);
                asm volatile("s_waitcnt lgkmcnt(0)" ::: "memory");
                __builtin_amdgcn_sched_barrier(0);
                __builtin_amdgcn_s_barrier();          // all waves done reading buf
                __builtin_amdgcn_sched_barrier(0);
                if (r < 7) stageS(s + 4, c);           // refill same buffer
                __builtin_amdgcn_s_setprio(1);
#pragma unroll
                for (int km = 0; km < 4; ++km)
#pragma unroll
                    for (int mt = 0; mt < 2; ++mt)
#pragma unroll
                        for (int nt = 0; nt < 2; ++nt)
                            acc2[mt][nt] = __builtin_amdgcn_mfma_f32_32x32x16_bf16(
                                af[mt][(h << 2) + km], bv[nt][km],
                                (h == 0 && km == 0) ? zero16 : acc2[mt][nt], 0, 0, 0);
                __builtin_amdgcn_s_setprio(0);
            }
            // fold: acc += e[row][r] * acc2; C/D row = (j&3) + 8*(j>>2) + 4*lhi
#pragma unroll
            for (int mt = 0; mt < 2; ++mt) {
#pragma unroll
                for (int rq = 0; rq < 4; ++rq) {
                    const f32x4 ev = *(const f32x4*)(ldsE + r * 128 + wr64 + mt * 32 + rq * 8 + lhi * 4);
#pragma unroll
                    for (int nt = 0; nt < 2; ++nt)
#pragma unroll
                        for (int jm = 0; jm < 4; ++jm)
                            acc[mt][nt][rq * 4 + jm] += ev[jm] * acc2[mt][nt][rq * 4 + jm];
                }
            }
        }
    }

    // ---- bias K=64 step: A-cols = e (built from ldsE), B = BtB tile
    __syncthreads();   // full drain; guards buffer overwrite
    {
        char* const bufB = lds;            // 16 KB
        char* const bufA = lds + 16384;    // 16 KB
#pragma unroll
        for (int rr = 0; rr < 4; ++rr) {
            const int q = rr * 256 + tid;
            GLOAD_LDS16(BtB + ((size_t)nb * 1024 + q) * 8, bufB + q * 16);
        }
#pragma unroll
        for (int rr = 0; rr < 4; ++rr) {
            const int q    = rr * 256 + tid;
            const int ln   = q & 63;
            const int f    = q >> 6;                       // mt*4 + ks16
            const int row  = ((f >> 2) << 5) + (ln & 31);
            const int kb   = ((f & 3) << 4) + ((ln >> 5) << 3);
            bf16x8 pv;
#pragma unroll
            for (int e8 = 0; e8 < 8; ++e8) {
                const int k = kb + e8;
                pv[e8] = (k < 9) ? (__bf16)ldsE[k * 128 + row] : (__bf16)0.f;
            }
            *(bf16x8*)(bufA + q * 16) = pv;
        }
        __syncthreads();
#pragma unroll
        for (int ks = 0; ks < 4; ++ks) {
            bf16x8 av[2], bv[2];
#pragma unroll
            for (int mt = 0; mt < 2; ++mt)
                av[mt] = *(const bf16x8*)(bufA + (((((mtb + mt) << 2) + ks) << 6) + lane) * 16);
#pragma unroll
            for (int nt = 0; nt < 2; ++nt)
                bv[nt] = *(const bf16x8*)(bufB + (((((ntb + nt) << 2) + ks) << 6) + lane) * 16);
#pragma unroll
            for (int mt = 0; mt < 2; ++mt)
#pragma unroll
                for (int nt = 0; nt < 2; ++nt)
                    acc[mt][nt] = __builtin_amdgcn_mfma_f32_32x32x16_bf16(
                        av[mt], bv[nt], acc[mt][nt], 0, 0, 0);
        }
    }

    // ---- epilogue: C/D col = l31 (per 32-tile), row = (j&3)+8*(j>>2)+4*lhi
    if (OUTF32) {
#pragma unroll
        for (int mt = 0; mt < 2; ++mt)
#pragma unroll
            for (int nt = 0; nt < 2; ++nt) {
                const int col = bn0 + ((ntb + nt) << 5) + l31;
#pragma unroll
                for (int rq = 0; rq < 4; ++rq)
#pragma unroll
                    for (int jm = 0; jm < 4; ++jm) {
                        const int row = bm0 + wr64 + mt * 32 + rq * 8 + lhi * 4 + jm;
                        float v = acc[mt][nt][rq * 4 + jm];
                        if (RELU) v = fmaxf(v, 0.f);
                        ((float*)Outv)[(size_t)row * O + col] = v;
                    }
            }
    } else {
        // write next layer's A in 32x32 frag-major (I' = O)
        constexpr int NCHn = O >> 7;
        __bf16* outp = (__bf16*)Outv;
#pragma unroll
        for (int mt = 0; mt < 2; ++mt) {
#pragma unroll
            for (int nt = 0; nt < 2; ++nt) {
                const int col   = bn0 + ((ntb + nt) << 5) + l31;
                const int c2    = col >> 7;
                const int ks2   = (col & 127) >> 4;
                const int lhi2  = ((l31 >> 3) & 1) << 5;
                const int e2    = col & 7;
                const int f2    = ((mtb + mt) << 3) + ks2;
                const size_t ub = ((size_t)(rb * NCHn + c2) * 2048 + f2 * 64 + lhi2);
#pragma unroll
                for (int rq = 0; rq < 4; ++rq)
#pragma unroll
                    for (int jm = 0; jm < 4; ++jm) {
                        const int rlow = rq * 8 + lhi * 4 + jm;   // row & 31
                        float v = acc[mt][nt][rq * 4 + jm];
                        if (RELU) v = fmaxf(v, 0.f);
                        outp[(ub + rlow) * 8 + e2] = (__bf16)v;
                    }
            }
        }
    }
}

// ---------------------------------------------------------------------------
extern "C" void kernel_launch(void* const* d_in, const int* in_sizes, int n_in,
                              void* d_out, int out_size, void* d_ws, size_t ws_size,
                              hipStream_t stream) {
    const float* x  = (const float*)d_in[0];
    const float* E  = (const float*)d_in[1];
    const float* W0 = (const float*)d_in[2];
    const float* b0 = (const float*)d_in[3];
    const float* W1 = (const float*)d_in[4];
    const float* b1 = (const float*)d_in[5];
    const float* W2 = (const float*)d_in[6];
    const float* b2 = (const float*)d_in[7];
    const float* W3 = (const float*)d_in[8];
    const float* b3 = (const float*)d_in[9];

    char* ws = (char*)d_ws;
    const size_t actBytes = (size_t)65536 * 512 * 2;           // 64 MiB each
    __bf16* actA = (__bf16*)ws;
    __bf16* actB = (__bf16*)(ws + actBytes);
    char* p = ws + 2 * actBytes;
    __bf16* Bt0 = (__bf16*)p; p += (size_t)4 * 9 * 2 * 2048 * 16;
    __bf16* Bt1 = (__bf16*)p; p += (size_t)4 * 9 * 4 * 2048 * 16;
    __bf16* Bt2 = (__bf16*)p; p += (size_t)4 * 9 * 4 * 2048 * 16;
    __bf16* Bt3 = (__bf16*)p; p += (size_t)2 * 9 * 4 * 2048 * 16;
    __bf16* BtB0 = (__bf16*)p; p += (size_t)4 * 1024 * 16;
    __bf16* BtB1 = (__bf16*)p; p += (size_t)4 * 1024 * 16;
    __bf16* BtB2 = (__bf16*)p; p += (size_t)4 * 1024 * 16;
    __bf16* BtB3 = (__bf16*)p; p += (size_t)2 * 1024 * 16;
    if (ws_size < (size_t)(p - ws)) return;   // ws too small -> visible failure

    // prep (all 32x32 frag-major; Bt half-contiguous)
    cvt_x_kernel<<<dim3(8192), dim3(256), 0, stream>>>(x, actA);
    prep_w_kernel<256, 512><<<dim3(16, 9, 4), dim3(256), 0, stream>>>(W0, Bt0);
    prep_w_kernel<512, 512><<<dim3(32, 9, 4), dim3(256), 0, stream>>>(W1, Bt1);
    prep_w_kernel<512, 512><<<dim3(32, 9, 4), dim3(256), 0, stream>>>(W2, Bt2);
    prep_w_kernel<512, 256><<<dim3(32, 9, 2), dim3(256), 0, stream>>>(W3, Bt3);
    prep_bias_kernel<512><<<dim3(16), dim3(256), 0, stream>>>(b0, BtB0);
    prep_bias_kernel<512><<<dim3(16), dim3(256), 0, stream>>>(b1, BtB1);
    prep_bias_kernel<512><<<dim3(16), dim3(256), 0, stream>>>(b2, BtB2);
    prep_bias_kernel<256><<<dim3(8),  dim3(256), 0, stream>>>(b3, BtB3);

    // 4 fused layers
    kg_gemm<256, 512, true,  false><<<dim3(2048), dim3(256), 0, stream>>>(actA, E, Bt0, BtB0, actB);
    kg_gemm<512, 512, true,  false><<<dim3(2048), dim3(256), 0, stream>>>(actB, E, Bt1, BtB1, actA);
    kg_gemm<512, 512, true,  false><<<dim3(2048), dim3(256), 0, stream>>>(actA, E, Bt2, BtB2, actB);
    kg_gemm<512, 256, false, true ><<<dim3(1024), dim3(256), 0, stream>>>(actB, E, Bt3, BtB3, d_out);
}